// Round 1
// baseline (345.077 us; speedup 1.0000x reference)
//
#include <hip/hip_runtime.h>

#define H 1024
#define E 64
#define BT 64
#define BK 64

// Tile GEMM: C[64 tok][64 exp] per block, K-chunked by 64.
// 256 threads: tx = expert group (16x4), ty = token group (16x4).
// LDS rows padded +4 floats (stride 68: keeps 16B alignment for b128,
// 68%32=4 -> b-fragment reads are 2-way bank aliased = free on CDNA4).
__global__ __launch_bounds__(256) void moe_gate_kernel(
    const float* __restrict__ x, const float* __restrict__ W,
    float* __restrict__ out, int T) {
  __shared__ float xs[BT][BK + 4];
  __shared__ float ws[E][BK + 4];
  __shared__ float ls[BT][65];  // logits tile for epilogue, stride 65 -> conflict-free

  const int tid = threadIdx.x;
  const int tx = tid & 15;   // expert group
  const int ty = tid >> 4;   // token group
  const int t0 = blockIdx.x * BT;

  float acc[4][4];
#pragma unroll
  for (int r = 0; r < 4; ++r)
#pragma unroll
    for (int c = 0; c < 4; ++c) acc[r][c] = 0.f;

  for (int k0 = 0; k0 < H; k0 += BK) {
    // Stage x-tile [64 x 64] and W-tile [64 x 64]: 4 float4 each per thread.
    // Coalesced: 16 consecutive lanes read 256 contiguous bytes per row.
#pragma unroll
    for (int l = 0; l < 4; ++l) {
      int id = tid + l * 256;       // 0..1023 float4 slots
      int row = id >> 4;            // 0..63
      int c4 = (id & 15) << 2;      // 0,4,...,60
      *(float4*)&xs[row][c4] = *(const float4*)&x[(size_t)(t0 + row) * H + k0 + c4];
      *(float4*)&ws[row][c4] = *(const float4*)&W[(size_t)row * H + k0 + c4];
    }
    __syncthreads();

#pragma unroll
    for (int kk = 0; kk < BK; kk += 4) {
      float4 a[4], b[4];
#pragma unroll
      for (int r = 0; r < 4; ++r) a[r] = *(const float4*)&xs[ty * 4 + r][kk];
#pragma unroll
      for (int c = 0; c < 4; ++c) b[c] = *(const float4*)&ws[tx * 4 + c][kk];
#pragma unroll
      for (int r = 0; r < 4; ++r)
#pragma unroll
        for (int c = 0; c < 4; ++c) {
          acc[r][c] += a[r].x * b[c].x;
          acc[r][c] += a[r].y * b[c].y;
          acc[r][c] += a[r].z * b[c].z;
          acc[r][c] += a[r].w * b[c].w;
        }
    }
    __syncthreads();
  }

  // Dump logits tile to LDS for the per-token epilogue.
#pragma unroll
  for (int r = 0; r < 4; ++r)
#pragma unroll
    for (int c = 0; c < 4; ++c) ls[ty * 4 + r][tx * 4 + c] = acc[r][c];
  __syncthreads();

  // Wave 0: one lane per token. top-2 of logits == top-2 of softmax
  // (monotonic); tie-break = lower index first (matches jax.lax.top_k).
  if (tid < BT) {
    const int tk = tid;
    float m1 = -1e30f, m2 = -1e30f;
    int i1 = 0, i2 = 0;
#pragma unroll
    for (int e = 0; e < E; ++e) {
      float v = ls[tk][e];
      if (v > m1) {
        m2 = m1; i2 = i1;
        m1 = v;  i1 = e;
      } else if (v > m2) {
        m2 = v; i2 = e;
      }
    }
    float s = 0.f;
#pragma unroll
    for (int e = 0; e < E; ++e) s += expf(ls[tk][e] - m1);
    // softmax probabilities of the top-2
    float p1 = 1.f / s;                 // exp(m1-m1)/s
    float p2 = expf(m2 - m1) / s;
    // second softmax over [p1, p2] (p1 >= p2 so exponent <= 0: stable)
    float e12 = expf(p2 - p1);
    float s1 = 1.f / (1.f + e12);
    float s2 = e12 * s1;

    size_t t = (size_t)(t0 + tk);
    out[t * 2 + 0] = s1;
    out[t * 2 + 1] = s2;
    float* idxo = out + (size_t)2 * T;
    idxo[t * 2 + 0] = (float)i1;
    idxo[t * 2 + 1] = (float)i2;
  }

  // trailing scalar output: zeros(())
  if (blockIdx.x == 0 && tid == 0) out[(size_t)4 * T] = 0.f;
}

extern "C" void kernel_launch(void* const* d_in, const int* in_sizes, int n_in,
                              void* d_out, int out_size, void* d_ws, size_t ws_size,
                              hipStream_t stream) {
  const float* x = (const float*)d_in[0];
  const float* W = (const float*)d_in[1];
  float* out = (float*)d_out;
  const int T = in_sizes[0] / H;  // 4*8192 = 32768 tokens
  dim3 grid(T / BT), block(256);
  hipLaunchKernelGGL(moe_gate_kernel, grid, block, 0, stream, x, W, out, T);
}

// Round 2
// 231.730 us; speedup vs baseline: 1.4891x; 1.4891x over previous
//
#include <hip/hip_runtime.h>

#define H 1024
#define E 64
#define BT 64
#define BK 64

// Tile GEMM: C[64 tok][64 exp] per block, K-chunked by 64.
// 256 threads: tx = expert group (16x4), ty = token group (16x4).
// xs: stride 68 floats (17 f4, 16B-aligned rows). a-reads have only 4
//   distinct ty-rows/wave -> 2-way bank aliasing = free (m136).
// ws: SAME stride but XOR-swizzled f4 column (phys = c4 ^ (row>>2)).
//   b-reads hit rows 4tx+c (16 distinct tx): unswizzled this is 8-way
//   conflict (the R1 6.96e7 SQ_LDS_BANK_CONFLICT); swizzled, bank-group
//   (4tx + c + (kkf^tx)) mod 8 is a permutation in tx mod 8 -> 2-way = free.
__global__ __launch_bounds__(256) void moe_gate_kernel(
    const float* __restrict__ x, const float* __restrict__ W,
    float* __restrict__ out, int T) {
  __shared__ float xs[BT][BK + 4];
  __shared__ float ws[E][BK + 4];
  // epilogue logits tile overlays xs (dead after K-loop); stride 65 -> conflict-free
  float(*ls)[65] = (float(*)[65])xs;

  const int tid = threadIdx.x;
  const int tx = tid & 15;   // expert group
  const int ty = tid >> 4;   // token group
  const int t0 = blockIdx.x * BT;

  float acc[4][4];
#pragma unroll
  for (int r = 0; r < 4; ++r)
#pragma unroll
    for (int c = 0; c < 4; ++c) acc[r][c] = 0.f;

  for (int k0 = 0; k0 < H; k0 += BK) {
    // Stage x-tile and W-tile [64 x 64]: 4 float4 each per thread, coalesced.
#pragma unroll
    for (int l = 0; l < 4; ++l) {
      int id = tid + l * 256;       // 0..1023 float4 slots
      int row = id >> 4;            // 0..63
      int c4 = id & 15;             // f4 column 0..15
      *(float4*)&xs[row][c4 << 2] =
          *(const float4*)&x[(size_t)(t0 + row) * H + k0 + (c4 << 2)];
      int wc = c4 ^ (row >> 2);     // XOR swizzle
      *(float4*)&ws[row][wc << 2] =
          *(const float4*)&W[(size_t)row * H + k0 + (c4 << 2)];
    }
    __syncthreads();

#pragma unroll
    for (int kk = 0; kk < BK; kk += 4) {
      const int kkf = kk >> 2;
      float4 a[4], b[4];
#pragma unroll
      for (int r = 0; r < 4; ++r) a[r] = *(const float4*)&xs[ty * 4 + r][kk];
#pragma unroll
      for (int c = 0; c < 4; ++c)
        b[c] = *(const float4*)&ws[tx * 4 + c][(kkf ^ tx) << 2];
#pragma unroll
      for (int r = 0; r < 4; ++r)
#pragma unroll
        for (int c = 0; c < 4; ++c) {
          acc[r][c] += a[r].x * b[c].x;
          acc[r][c] += a[r].y * b[c].y;
          acc[r][c] += a[r].z * b[c].z;
          acc[r][c] += a[r].w * b[c].w;
        }
    }
    __syncthreads();
  }

  // Dump logits tile to LDS (overlaying xs) for the per-token epilogue.
#pragma unroll
  for (int r = 0; r < 4; ++r)
#pragma unroll
    for (int c = 0; c < 4; ++c) ls[ty * 4 + r][tx * 4 + c] = acc[r][c];
  __syncthreads();

  // Wave 0: one lane per token. top-2 of logits == top-2 of softmax
  // (monotonic); tie-break = lower index first (matches jax.lax.top_k).
  if (tid < BT) {
    const int tk = tid;
    float m1 = -1e30f, m2 = -1e30f;
    int i1 = 0, i2 = 0;
#pragma unroll
    for (int e = 0; e < E; ++e) {
      float v = ls[tk][e];
      if (v > m1) {
        m2 = m1; i2 = i1;
        m1 = v;  i1 = e;
      } else if (v > m2) {
        m2 = v; i2 = e;
      }
    }
    float s = 0.f;
#pragma unroll
    for (int e = 0; e < E; ++e) s += expf(ls[tk][e] - m1);
    // softmax probabilities of the top-2
    float p1 = 1.f / s;                 // exp(m1-m1)/s
    float p2 = expf(m2 - m1) / s;
    // second softmax over [p1, p2] (p1 >= p2 so exponent <= 0: stable)
    float e12 = expf(p2 - p1);
    float s1 = 1.f / (1.f + e12);
    float s2 = e12 * s1;

    size_t t = (size_t)(t0 + tk);
    out[t * 2 + 0] = s1;
    out[t * 2 + 1] = s2;
    float* idxo = out + (size_t)2 * T;
    idxo[t * 2 + 0] = (float)i1;
    idxo[t * 2 + 1] = (float)i2;
  }

  // trailing scalar output: zeros(())
  if (blockIdx.x == 0 && tid == 0) out[(size_t)4 * T] = 0.f;
}

extern "C" void kernel_launch(void* const* d_in, const int* in_sizes, int n_in,
                              void* d_out, int out_size, void* d_ws, size_t ws_size,
                              hipStream_t stream) {
  const float* x = (const float*)d_in[0];
  const float* W = (const float*)d_in[1];
  float* out = (float*)d_out;
  const int T = in_sizes[0] / H;  // 4*8192 = 32768 tokens
  dim3 grid(T / BT), block(256);
  hipLaunchKernelGGL(moe_gate_kernel, grid, block, 0, stream, x, W, out, T);
}